// Round 8
// baseline (3371.149 us; speedup 1.0000x reference)
//
#include <hip/hip_runtime.h>
#include <hip/hip_bf16.h>
#include <math.h>

#define SEQ   32
#define BATCH 1024
#define NN    19
#define HH    128
#define NB    4            /* batch elements per block */
#define MR    (NB*NN)      /* 76 rows per block */
#define SAS   264          /* sA row stride (bf16): 528 B = 16B-aligned, 4-bank shift */
#define HS    132          /* h row stride (elems) */
#define UTS   72           /* Ut row stride (bf16): 144 B = 16B-aligned rows */
#define NBLK  (BATCH/NB)   /* 256 blocks, 1 per CU */
#define NT    1024         /* 16 waves, 4 per SIMD */

typedef __attribute__((ext_vector_type(8))) short  bf16x8;
typedef __attribute__((ext_vector_type(4))) float  f32x4;
typedef __attribute__((ext_vector_type(2))) int    i32x2;

__device__ __forceinline__ unsigned short f2bf(float v) {
    __hip_bfloat16 b = __float2bfloat16(v);
    return *reinterpret_cast<unsigned short*>(&b);
}
__device__ __forceinline__ float bf2f(unsigned short u) {
    unsigned int x = ((unsigned int)u) << 16;
    return __uint_as_float(x);
}
__device__ __forceinline__ float hload(const unsigned short* p) { return bf2f(*p); }
__device__ __forceinline__ float hload(const float* p)          { return *p; }
__device__ __forceinline__ void  hstore(unsigned short* p, float v) { *p = f2bf(v); }
__device__ __forceinline__ void  hstore(float* p, float v)          { *p = v; }

// dequant 8 int8 -> bf16x8, one shared scale
__device__ __forceinline__ bf16x8 dq8(const signed char* p, float s) {
    i32x2 wv = *(const i32x2*)p;
    bf16x8 r;
    #pragma unroll
    for (int i = 0; i < 4; ++i) {
        int b0 = (wv.x << (24 - 8*i)) >> 24;   // sign-extended byte i
        r[i] = f2bf((float)b0 * s);
    }
    #pragma unroll
    for (int i = 0; i < 4; ++i) {
        int b1 = (wv.y << (24 - 8*i)) >> 24;
        r[4+i] = f2bf((float)b1 * s);
    }
    return r;
}

// ---------------------------------------------------------------------------
// Setup 1a: per-(j,col) dequant scale = absmax/127 over the K dim.
// ---------------------------------------------------------------------------
__global__ __launch_bounds__(256) void wscale_kernel(
    const float* __restrict__ W, float* __restrict__ scD, int F, int O)
{
    int row = blockIdx.x*256 + threadIdx.x;   // [0, 3*O)
    if (row >= 3*O) return;
    int j = row / O, col = row - j*O;
    float m = 0.f;
    for (int k = 0; k < F; ++k)
        m = fmaxf(m, fabsf(W[(size_t)(j*F + k)*O + col]));
    scD[row] = (m > 0.f) ? m * (1.f/127.f) : 1.f;
}

// ---------------------------------------------------------------------------
// Setup 1b: quantize + reorder/transpose: Q[j][col][k] = rint(W[j*F+k][col]/s)
// ---------------------------------------------------------------------------
__global__ __launch_bounds__(256) void wquant_kernel(
    const float* __restrict__ W, const float* __restrict__ scD,
    signed char* __restrict__ Q, int F, int O, int KP)
{
    int idx = blockIdx.x*256 + threadIdx.x;
    int total = 3*O*KP;
    if (idx >= total) return;
    int j   = idx / (O*KP);
    int r   = idx - j*(O*KP);
    int col = r / KP;
    int k   = r - col*KP;
    float v = (k < F) ? W[(size_t)(j*F + k)*O + col] : 0.f;
    float s = scD[j*O + col];
    int q = (int)rintf(v / s);
    q = q > 127 ? 127 : (q < -127 ? -127 : q);
    Q[idx] = (signed char)q;
}

// ---------------------------------------------------------------------------
// Setup 2: T' (32 x 64) bf16: T'[m][j*19+n] = Tj[m,n]; T0=I, T1=S, T2=2S^2-I.
// ---------------------------------------------------------------------------
__global__ __launch_bounds__(256) void tprime_kernel(
    const float* __restrict__ S, unsigned short* __restrict__ Tg)
{
    __shared__ float sS[NN*NN], sS2[NN*NN];
    int tid = threadIdx.x;
    for (int i = tid; i < NN*NN; i += 256) sS[i] = S[i];
    __syncthreads();
    for (int i = tid; i < NN*NN; i += 256) {
        int m = i/NN, n = i - m*NN;
        float a = 0.f;
        for (int k = 0; k < NN; ++k) a += sS[m*NN+k]*sS[k*NN+n];
        sS2[i] = a;
    }
    __syncthreads();
    for (int i = tid; i < 32*64; i += 256) {
        int m = i >> 6, k = i & 63;
        float v = 0.f;
        if (m < NN && k < 3*NN) {
            int j = k / NN, n = k - j*NN;
            float eye = (m == n) ? 1.f : 0.f;
            if (j == 0)      v = eye;
            else if (j == 1) v = sS[m*NN+n];
            else             v = 2.f*sS2[m*NN+n] - eye;
        }
        Tg[i] = f2bf(v);
    }
}

// ---------------------------------------------------------------------------
// Persistent kernel: 256 blocks x 1024 threads (16 waves, 4/SIMD).
// ---------------------------------------------------------------------------
#define LDS_BYTES 159664

template<int KS, int OC, bool GATE, int XW, typename HT>
__device__ __forceinline__ void gconv_phase(
    const signed char* __restrict__ BQ,      // (3, OC, KS*32) int8
    const float* __restrict__ scD,           // (3*OC) dequant scales
    const float* __restrict__ bias,
    HT* hL,
    unsigned short* sA,
    unsigned short* ub,
    unsigned short* UtW,                     // this wave's slab (16 x UTS)
    const bf16x8 (&tp)[2][2],
    int lane, int sgo)                       // sgo = this wave's 16-col base
{
    constexpr int KP = KS*32;
    const int r16 = lane & 15, quad = lane >> 4;

    float ws3[3];
    #pragma unroll
    for (int j = 0; j < 3; ++j) ws3[j] = scD[j*OC + sgo + r16];

    f32x4 acc[3][5];
    #pragma unroll
    for (int j = 0; j < 3; ++j)
        #pragma unroll
        for (int mt = 0; mt < 5; ++mt) acc[j][mt] = (f32x4)0.f;

    // ---- main MFMA: U_j = x0 @ W_j for this wave's 16 cols ----
    #pragma unroll
    for (int ks = 0; ks < KS; ++ks) {
        bf16x8 af[5];
        #pragma unroll
        for (int mt = 0; mt < 5; ++mt)
            af[mt] = *(const bf16x8*)&sA[(mt*16 + r16)*SAS + ks*32 + quad*8];
        #pragma unroll
        for (int j = 0; j < 3; ++j) {
            const signed char* gp =
                BQ + (size_t)(j*OC + sgo + r16)*KP + ks*32 + quad*8;
            bf16x8 bf = dq8(gp, ws3[j]);
            #pragma unroll
            for (int mt = 0; mt < 5; ++mt)
                acc[j][mt] = __builtin_amdgcn_mfma_f32_16x16x32_bf16(
                    af[mt], bf, acc[j][mt], 0, 0, 0);
        }
    }

    if (GATE) __syncthreads();   // gate epilogue rewrites sA (r*h)

    const float bv = bias[sgo + r16];

    for (int b = 0; b < NB; ++b) {
        // scatter this batch's node rows into Ut (row = out col, col = j*19+n)
        #pragma unroll
        for (int j = 0; j < 3; ++j)
            #pragma unroll
            for (int mt = 0; mt < 5; ++mt)
                #pragma unroll
                for (int reg = 0; reg < 4; ++reg) {
                    int gm = mt*16 + quad*4 + reg;
                    int n  = gm - b*NN;
                    if (n >= 0 && n < NN)
                        UtW[r16*UTS + j*NN + n] = f2bf(acc[j][mt][reg]);
                }
        // mixing: y = T' @ U
        f32x4 y[2];
        y[0] = (f32x4)0.f; y[1] = (f32x4)0.f;
        #pragma unroll
        for (int kk = 0; kk < 2; ++kk) {
            bf16x8 uf = *(const bf16x8*)&UtW[r16*UTS + kk*32 + quad*8];
            y[0] = __builtin_amdgcn_mfma_f32_16x16x32_bf16(tp[0][kk], uf, y[0], 0, 0, 0);
            y[1] = __builtin_amdgcn_mfma_f32_16x16x32_bf16(tp[1][kk], uf, y[1], 0, 0, 0);
        }
        // epilogue
        #pragma unroll
        for (int mt2 = 0; mt2 < 2; ++mt2)
            #pragma unroll
            for (int reg = 0; reg < 4; ++reg) {
                int m = mt2*16 + quad*4 + reg;
                if (m < NN) {
                    int o = sgo + r16;
                    float v = y[mt2][reg] + bv;
                    int row = b*NN + m;
                    if (GATE) {
                        float sg_ = 1.f/(1.f + __expf(-v));
                        if (o < HH)
                            sA[row*SAS + XW + o] = f2bf(sg_ * hload(&hL[row*HS + o]));
                        else
                            ub[row*HS + (o-HH)] = f2bf(sg_);
                    } else {
                        float c  = 2.f/(1.f + __expf(-2.f*v)) - 1.f;
                        float u  = bf2f(ub[row*HS + o]);
                        float ho = hload(&hL[row*HS + o]);
                        hstore(&hL[row*HS + o], u*ho + (1.f - u)*c);
                    }
                }
            }
    }
}

__global__ __launch_bounds__(NT, 4) void dcgru_persistent(
    const float* __restrict__ ihs,
    const signed char* __restrict__ Qg0, const float* __restrict__ Sg0, const float* __restrict__ bg0,
    const signed char* __restrict__ Qc0, const float* __restrict__ Sc0, const float* __restrict__ bc0,
    const signed char* __restrict__ Qg1, const float* __restrict__ Sg1, const float* __restrict__ bg1,
    const signed char* __restrict__ Qc1, const float* __restrict__ Sc1, const float* __restrict__ bc1,
    const float* __restrict__ Wp, const float* __restrict__ bp,
    const unsigned short* __restrict__ Tg,
    float* __restrict__ out)
{
    extern __shared__ char smem[];
    unsigned short* h0    = (unsigned short*)smem;                 // 20064
    float*          h1    = (float*)(smem + 20064);                // 40128
    unsigned short* sA    = (unsigned short*)(smem + 60192);       // 42240
    unsigned short* ub    = (unsigned short*)(smem + 102432);      // 20064
    unsigned short* Ut    = (unsigned short*)(smem + 122496);      // 36864
    float*          xprev = (float*)(smem + 159360);               // 304

    const int tid  = threadIdx.x;
    const int lane = tid & 63;
    const int w    = tid >> 6;          // 0..15
    const int bb   = blockIdx.x * NB;
    unsigned short* UtW = Ut + w*16*UTS;

    for (int i = tid; i < MR*HH; i += NT) {
        int row = i >> 7, f = i & 127;
        h0[row*HS + f] = f2bf(ihs[(size_t)bb*2432 + i]);
        h1[row*HS + f] = ihs[(size_t)(BATCH + bb)*2432 + i];
    }
    for (int i = tid; i < MR; i += NT) xprev[i] = 0.f;
    for (int i = lane; i < 16*UTS; i += 64) UtW[i] = 0;

    bf16x8 tp[2][2];
    {
        const int r16 = lane & 15, quad = lane >> 4;
        #pragma unroll
        for (int mt2 = 0; mt2 < 2; ++mt2)
            #pragma unroll
            for (int kk = 0; kk < 2; ++kk)
                tp[mt2][kk] = *(const bf16x8*)&Tg[(mt2*16 + r16)*64 + kk*32 + quad*8];
    }
    const float wp0 = Wp[lane], wp1 = Wp[64 + lane], bpv = bp[0];
    __syncthreads();

    for (int t = 0; t < SEQ; ++t) {
        // ---- layer 0: sA = [xprev | h0 | 0-pad]  (K = 160) ----
        for (int idx = tid; idx < MR*160; idx += NT) {
            int row = idx/160, c = idx - row*160;
            unsigned short v;
            if (c == 0)       v = f2bf(xprev[row]);
            else if (c <= HH) v = h0[row*HS + (c-1)];
            else              v = 0;
            sA[row*SAS + c] = v;
        }
        __syncthreads();
        gconv_phase<5,256,true ,1>(Qg0, Sg0, bg0, h0, sA, ub, UtW, tp, lane, w*16);
        __syncthreads();
        if (w < 8)
            gconv_phase<5,128,false,1>(Qc0, Sc0, bc0, h0, sA, ub, UtW, tp, lane, w*16);
        __syncthreads();

        // ---- layer 1: sA = [h0 | h1]  (K = 256) ----
        for (int idx = tid; idx < MR*256; idx += NT) {
            int row = idx >> 8, c = idx & 255;
            sA[row*SAS + c] = (c < HH) ? h0[row*HS + c]
                                       : f2bf(h1[row*HS + (c-HH)]);
        }
        __syncthreads();
        gconv_phase<8,256,true ,HH>(Qg1, Sg1, bg1, h1, sA, ub, UtW, tp, lane, w*16);
        __syncthreads();
        if (w < 8)
            gconv_phase<8,128,false,HH>(Qc1, Sc1, bc1, h1, sA, ub, UtW, tp, lane, w*16);
        __syncthreads();

        // ---- projection: wave w -> batch w>>2, quarter of the nodes ----
        {
            int b  = w >> 2;
            int q  = w & 3;
            int n0 = q*5;
            int n1 = (q == 3) ? NN : n0 + 5;
            for (int n = n0; n < n1; ++n) {
                int row = b*NN + n;
                float s = h1[row*HS + lane]*wp0 + h1[row*HS + 64 + lane]*wp1;
                #pragma unroll
                for (int off = 32; off; off >>= 1) s += __shfl_down(s, off, 64);
                if (lane == 0) {
                    float v = s + bpv;
                    out[((size_t)t*BATCH + bb + b)*NN + n] = v;
                    xprev[row] = v;
                }
            }
        }
        __syncthreads();
    }
}

// ---------------------------------------------------------------------------
extern "C" void kernel_launch(void* const* d_in, const int* in_sizes, int n_in,
                              void* d_out, int out_size, void* d_ws, size_t ws_size,
                              hipStream_t stream) {
    const float* ihs = (const float*)d_in[1];
    const float* S   = (const float*)d_in[2];
    const float* Wg0 = (const float*)d_in[3];
    const float* bg0 = (const float*)d_in[4];
    const float* Wc0 = (const float*)d_in[5];
    const float* bc0 = (const float*)d_in[6];
    const float* Wg1 = (const float*)d_in[7];
    const float* bg1 = (const float*)d_in[8];
    const float* Wc1 = (const float*)d_in[9];
    const float* bc1 = (const float*)d_in[10];
    const float* Wp  = (const float*)d_in[11];
    const float* bp  = (const float*)d_in[12];
    float* out = (float*)d_out;

    char* ws = (char*)d_ws;
    unsigned short* Tg = (unsigned short*)ws;              // 4096 B
    signed char* Qg0 = (signed char*)(ws + 4096);          // 3*256*160 = 122880
    signed char* Qc0 = (signed char*)(ws + 126976);        // 3*128*160 =  61440
    signed char* Qg1 = (signed char*)(ws + 188416);        // 3*256*256 = 196608
    signed char* Qc1 = (signed char*)(ws + 385024);        // 3*128*256 =  98304
    float* Sg0 = (float*)(ws + 483328);                    // 768*4
    float* Sc0 = (float*)(ws + 486400);                    // 384*4
    float* Sg1 = (float*)(ws + 487936);                    // 768*4
    float* Sc1 = (float*)(ws + 491008);                    // 384*4

    tprime_kernel<<<1, 256, 0, stream>>>(S, Tg);
    wscale_kernel<<<3, 256, 0, stream>>>(Wg0, Sg0, 129, 256);
    wscale_kernel<<<2, 256, 0, stream>>>(Wc0, Sc0, 129, 128);
    wscale_kernel<<<3, 256, 0, stream>>>(Wg1, Sg1, 256, 256);
    wscale_kernel<<<2, 256, 0, stream>>>(Wc1, Sc1, 256, 128);
    wquant_kernel<<<(3*256*160+255)/256, 256, 0, stream>>>(Wg0, Sg0, Qg0, 129, 256, 160);
    wquant_kernel<<<(3*128*160+255)/256, 256, 0, stream>>>(Wc0, Sc0, Qc0, 129, 128, 160);
    wquant_kernel<<<(3*256*256+255)/256, 256, 0, stream>>>(Wg1, Sg1, Qg1, 256, 256, 256);
    wquant_kernel<<<(3*128*256+255)/256, 256, 0, stream>>>(Wc1, Sc1, Qc1, 256, 128, 256);

    hipFuncSetAttribute((const void*)dcgru_persistent,
                        hipFuncAttributeMaxDynamicSharedMemorySize, LDS_BYTES);

    dcgru_persistent<<<NBLK, NT, LDS_BYTES, stream>>>(
        ihs, Qg0, Sg0, bg0, Qc0, Sc0, bc0, Qg1, Sg1, bg1, Qc1, Sc1, bc1,
        Wp, bp, Tg, out);
}

// Round 9
// 3259.823 us; speedup vs baseline: 1.0342x; 1.0342x over previous
//
#include <hip/hip_runtime.h>
#include <hip/hip_bf16.h>
#include <math.h>

#define SEQ   32
#define BATCH 1024
#define NN    19
#define HH    128
#define NB    4            /* batch elements per block */
#define MR    (NB*NN)      /* 76 rows per block */
#define SAS   264          /* sA row stride (bf16): 528 B = 16B-aligned, 4-bank shift */
#define HS    132          /* h row stride (elems) */
#define UTS   72           /* Ut row stride (bf16): 144 B = 16B-aligned rows */
#define NBLK  (BATCH/NB)   /* 256 blocks, 1 per CU */
#define NT    1024         /* 16 waves, 4 per SIMD */

typedef __attribute__((ext_vector_type(8))) short  bf16x8;
typedef __attribute__((ext_vector_type(4))) float  f32x4;
typedef __attribute__((ext_vector_type(4))) int    i32x4;

__device__ __forceinline__ unsigned short f2bf(float v) {
    __hip_bfloat16 b = __float2bfloat16(v);
    return *reinterpret_cast<unsigned short*>(&b);
}
__device__ __forceinline__ float bf2f(unsigned short u) {
    unsigned int x = ((unsigned int)u) << 16;
    return __uint_as_float(x);
}
__device__ __forceinline__ float hload(const unsigned short* p) { return bf2f(*p); }
__device__ __forceinline__ float hload(const float* p)          { return *p; }
__device__ __forceinline__ void  hstore(unsigned short* p, float v) { *p = f2bf(v); }
__device__ __forceinline__ void  hstore(float* p, float v)          { *p = v; }

// dequant 8 int8 (two i32) -> bf16x8, one shared scale
__device__ __forceinline__ bf16x8 dqh(int lo, int hi, float s) {
    bf16x8 r;
    #pragma unroll
    for (int i = 0; i < 4; ++i)
        r[i]   = f2bf((float)((lo << (24 - 8*i)) >> 24) * s);
    #pragma unroll
    for (int i = 0; i < 4; ++i)
        r[4+i] = f2bf((float)((hi << (24 - 8*i)) >> 24) * s);
    return r;
}

// ---------------------------------------------------------------------------
// Setup 1a: per-(j,col) dequant scale = absmax/127 over the K dim.
// ---------------------------------------------------------------------------
__global__ __launch_bounds__(256) void wscale_kernel(
    const float* __restrict__ W, float* __restrict__ scD, int F, int O)
{
    int row = blockIdx.x*256 + threadIdx.x;   // [0, 3*O)
    if (row >= 3*O) return;
    int j = row / O, col = row - j*O;
    float m = 0.f;
    for (int k = 0; k < F; ++k)
        m = fmaxf(m, fabsf(W[(size_t)(j*F + k)*O + col]));
    scD[row] = (m > 0.f) ? m * (1.f/127.f) : 1.f;
}

// ---------------------------------------------------------------------------
// Setup 1b: quantize + transpose + fragment-permute.
// Within each PB-sized K-block: packed offset q*(PB/4)+s*8+i <-> k=s*32+q*8+i
// so a lane's 16 B load = frag halves for MFMA steps (l*2, l*2+1).
// ---------------------------------------------------------------------------
__global__ __launch_bounds__(256) void wquant_kernel(
    const float* __restrict__ W, const float* __restrict__ scD,
    signed char* __restrict__ Q, int F, int O, int KP, int PB)
{
    int idx = blockIdx.x*256 + threadIdx.x;
    int total = 3*O*KP;
    if (idx >= total) return;
    int j   = idx / (O*KP);
    int r   = idx - j*(O*KP);
    int col = r / KP;
    int kp  = r - col*KP;
    int kb  = kp / PB;
    int r2  = kp - kb*PB;
    int q   = r2 / (PB/4);
    int r3  = r2 - q*(PB/4);
    int s   = r3 >> 3;
    int i   = r3 & 7;
    int k   = kb*PB + s*32 + q*8 + i;
    float v = (k < F) ? W[(size_t)(j*F + k)*O + col] : 0.f;
    float sc = scD[j*O + col];
    int qv = (int)rintf(v / sc);
    qv = qv > 127 ? 127 : (qv < -127 ? -127 : qv);
    Q[idx] = (signed char)qv;
}

// ---------------------------------------------------------------------------
// Setup 2: T' (32 x 64) bf16: T'[m][j*19+n] = Tj[m,n]; T0=I, T1=S, T2=2S^2-I.
// ---------------------------------------------------------------------------
__global__ __launch_bounds__(256) void tprime_kernel(
    const float* __restrict__ S, unsigned short* __restrict__ Tg)
{
    __shared__ float sS[NN*NN], sS2[NN*NN];
    int tid = threadIdx.x;
    for (int i = tid; i < NN*NN; i += 256) sS[i] = S[i];
    __syncthreads();
    for (int i = tid; i < NN*NN; i += 256) {
        int m = i/NN, n = i - m*NN;
        float a = 0.f;
        for (int k = 0; k < NN; ++k) a += sS[m*NN+k]*sS[k*NN+n];
        sS2[i] = a;
    }
    __syncthreads();
    for (int i = tid; i < 32*64; i += 256) {
        int m = i >> 6, k = i & 63;
        float v = 0.f;
        if (m < NN && k < 3*NN) {
            int j = k / NN, n = k - j*NN;
            float eye = (m == n) ? 1.f : 0.f;
            if (j == 0)      v = eye;
            else if (j == 1) v = sS[m*NN+n];
            else             v = 2.f*sS2[m*NN+n] - eye;
        }
        Tg[i] = f2bf(v);
    }
}

// ---------------------------------------------------------------------------
// Persistent kernel: 256 blocks x 1024 threads (16 waves, 4/SIMD).
// ---------------------------------------------------------------------------
#define LDS_BYTES 159664

template<int KP, int PB, int OC, bool GATE, int XW, typename HT>
__device__ __forceinline__ void gconv_phase(
    const signed char* __restrict__ BQ,      // (3, OC, KP) int8, fragment-packed
    const float* __restrict__ scD,           // (3*OC) dequant scales
    const float* __restrict__ bias,
    HT* hL,
    unsigned short* sA,
    unsigned short* ub,
    unsigned short* UtW,                     // this wave's slab (16 x UTS)
    const bf16x8 (&tp)[2][2],
    int lane, int sgo)                       // sgo = this wave's 16-col base
{
    const int r16 = lane & 15, quad = lane >> 4;

    float ws3[3];
    #pragma unroll
    for (int j = 0; j < 3; ++j) ws3[j] = scD[j*OC + sgo + r16];

    f32x4 acc[3][5];
    #pragma unroll
    for (int j = 0; j < 3; ++j)
        #pragma unroll
        for (int mt = 0; mt < 5; ++mt) acc[j][mt] = (f32x4)0.f;

    // ---- main MFMA: U_j = x0 @ W_j for this wave's 16 cols ----
    #pragma unroll
    for (int kb = 0; kb < KP/PB; ++kb) {
        #pragma unroll
        for (int l = 0; l < PB/64; ++l) {
            i32x4 wv[3];
            #pragma unroll
            for (int j = 0; j < 3; ++j)
                wv[j] = *(const i32x4*)(BQ +
                    (size_t)(j*OC + sgo + r16)*KP + kb*PB + quad*(PB/4) + l*16);
            #pragma unroll
            for (int h = 0; h < 2; ++h) {
                const int ks = kb*(PB/32) + l*2 + h;
                bf16x8 af[5];
                #pragma unroll
                for (int mt = 0; mt < 5; ++mt)
                    af[mt] = *(const bf16x8*)&sA[(mt*16 + r16)*SAS + ks*32 + quad*8];
                #pragma unroll
                for (int j = 0; j < 3; ++j) {
                    bf16x8 bf = dqh(wv[j][2*h], wv[j][2*h+1], ws3[j]);
                    #pragma unroll
                    for (int mt = 0; mt < 5; ++mt)
                        acc[j][mt] = __builtin_amdgcn_mfma_f32_16x16x32_bf16(
                            af[mt], bf, acc[j][mt], 0, 0, 0);
                }
            }
        }
    }

    if (GATE) __syncthreads();   // gate epilogue rewrites sA (r*h)

    const float bv = bias[sgo + r16];

    for (int b = 0; b < NB; ++b) {
        // scatter this batch's node rows into Ut (row = out col, col = j*19+n)
        #pragma unroll
        for (int j = 0; j < 3; ++j)
            #pragma unroll
            for (int mt = 0; mt < 5; ++mt)
                #pragma unroll
                for (int reg = 0; reg < 4; ++reg) {
                    int gm = mt*16 + quad*4 + reg;
                    int n  = gm - b*NN;
                    if (n >= 0 && n < NN)
                        UtW[r16*UTS + j*NN + n] = f2bf(acc[j][mt][reg]);
                }
        // mixing: y = T' @ U
        f32x4 y[2];
        y[0] = (f32x4)0.f; y[1] = (f32x4)0.f;
        #pragma unroll
        for (int kk = 0; kk < 2; ++kk) {
            bf16x8 uf = *(const bf16x8*)&UtW[r16*UTS + kk*32 + quad*8];
            y[0] = __builtin_amdgcn_mfma_f32_16x16x32_bf16(tp[0][kk], uf, y[0], 0, 0, 0);
            y[1] = __builtin_amdgcn_mfma_f32_16x16x32_bf16(tp[1][kk], uf, y[1], 0, 0, 0);
        }
        // epilogue
        #pragma unroll
        for (int mt2 = 0; mt2 < 2; ++mt2)
            #pragma unroll
            for (int reg = 0; reg < 4; ++reg) {
                int m = mt2*16 + quad*4 + reg;
                if (m < NN) {
                    int o = sgo + r16;
                    float v = y[mt2][reg] + bv;
                    int row = b*NN + m;
                    if (GATE) {
                        float sg_ = 1.f/(1.f + __expf(-v));
                        if (o < HH)
                            sA[row*SAS + XW + o] = f2bf(sg_ * hload(&hL[row*HS + o]));
                        else
                            ub[row*HS + (o-HH)] = f2bf(sg_);
                    } else {
                        float c  = 2.f/(1.f + __expf(-2.f*v)) - 1.f;
                        float u  = bf2f(ub[row*HS + o]);
                        float ho = hload(&hL[row*HS + o]);
                        hstore(&hL[row*HS + o], u*ho + (1.f - u)*c);
                    }
                }
            }
    }
}

__global__ __launch_bounds__(NT, 4) void dcgru_persistent(
    const float* __restrict__ ihs,
    const signed char* __restrict__ Qg0, const float* __restrict__ Sg0, const float* __restrict__ bg0,
    const signed char* __restrict__ Qc0, const float* __restrict__ Sc0, const float* __restrict__ bc0,
    const signed char* __restrict__ Qg1, const float* __restrict__ Sg1, const float* __restrict__ bg1,
    const signed char* __restrict__ Qc1, const float* __restrict__ Sc1, const float* __restrict__ bc1,
    const float* __restrict__ Wp, const float* __restrict__ bp,
    const unsigned short* __restrict__ Tg,
    float* __restrict__ out)
{
    extern __shared__ char smem[];
    unsigned short* h0    = (unsigned short*)smem;                 // 20064
    float*          h1    = (float*)(smem + 20064);                // 40128
    unsigned short* sA    = (unsigned short*)(smem + 60192);       // 42240
    unsigned short* ub    = (unsigned short*)(smem + 102432);      // 20064
    unsigned short* Ut    = (unsigned short*)(smem + 122496);      // 36864
    float*          xprev = (float*)(smem + 159360);               // 304

    const int tid  = threadIdx.x;
    const int lane = tid & 63;
    const int w    = tid >> 6;          // 0..15
    const int bb   = blockIdx.x * NB;
    unsigned short* UtW = Ut + w*16*UTS;

    for (int i = tid; i < MR*HH; i += NT) {
        int row = i >> 7, f = i & 127;
        h0[row*HS + f] = f2bf(ihs[(size_t)bb*2432 + i]);
        h1[row*HS + f] = ihs[(size_t)(BATCH + bb)*2432 + i];
    }
    for (int i = tid; i < MR; i += NT) xprev[i] = 0.f;
    for (int i = lane; i < 16*UTS; i += 64) UtW[i] = 0;

    bf16x8 tp[2][2];
    {
        const int r16 = lane & 15, quad = lane >> 4;
        #pragma unroll
        for (int mt2 = 0; mt2 < 2; ++mt2)
            #pragma unroll
            for (int kk = 0; kk < 2; ++kk)
                tp[mt2][kk] = *(const bf16x8*)&Tg[(mt2*16 + r16)*64 + kk*32 + quad*8];
    }
    const float wp0 = Wp[lane], wp1 = Wp[64 + lane], bpv = bp[0];
    __syncthreads();

    for (int t = 0; t < SEQ; ++t) {
        // ---- layer 0: sA = [xprev | h0 | 0-pad]  (K=129 padded to 192) ----
        for (int idx = tid; idx < MR*192; idx += NT) {
            int row = idx/192, c = idx - row*192;
            unsigned short v;
            if (c == 0)       v = f2bf(xprev[row]);
            else if (c <= HH) v = h0[row*HS + (c-1)];
            else              v = 0;
            sA[row*SAS + c] = v;
        }
        __syncthreads();
        gconv_phase<192,64,256,true ,1>(Qg0, Sg0, bg0, h0, sA, ub, UtW, tp, lane, w*16);
        __syncthreads();
        if (w < 8)
            gconv_phase<192,64,128,false,1>(Qc0, Sc0, bc0, h0, sA, ub, UtW, tp, lane, w*16);
        __syncthreads();

        // ---- layer 1: sA = [h0 | h1]  (K = 256) ----
        for (int idx = tid; idx < MR*256; idx += NT) {
            int row = idx >> 8, c = idx & 255;
            sA[row*SAS + c] = (c < HH) ? h0[row*HS + c]
                                       : f2bf(h1[row*HS + (c-HH)]);
        }
        __syncthreads();
        gconv_phase<256,128,256,true ,HH>(Qg1, Sg1, bg1, h1, sA, ub, UtW, tp, lane, w*16);
        __syncthreads();
        if (w < 8)
            gconv_phase<256,128,128,false,HH>(Qc1, Sc1, bc1, h1, sA, ub, UtW, tp, lane, w*16);
        __syncthreads();

        // ---- projection: wave w -> batch w>>2, quarter of the nodes ----
        {
            int b  = w >> 2;
            int q  = w & 3;
            int n0 = q*5;
            int n1 = (q == 3) ? NN : n0 + 5;
            for (int n = n0; n < n1; ++n) {
                int row = b*NN + n;
                float s = h1[row*HS + lane]*wp0 + h1[row*HS + 64 + lane]*wp1;
                #pragma unroll
                for (int off = 32; off; off >>= 1) s += __shfl_down(s, off, 64);
                if (lane == 0) {
                    float v = s + bpv;
                    out[((size_t)t*BATCH + bb + b)*NN + n] = v;
                    xprev[row] = v;
                }
            }
        }
        __syncthreads();
    }
}

// ---------------------------------------------------------------------------
extern "C" void kernel_launch(void* const* d_in, const int* in_sizes, int n_in,
                              void* d_out, int out_size, void* d_ws, size_t ws_size,
                              hipStream_t stream) {
    const float* ihs = (const float*)d_in[1];
    const float* S   = (const float*)d_in[2];
    const float* Wg0 = (const float*)d_in[3];
    const float* bg0 = (const float*)d_in[4];
    const float* Wc0 = (const float*)d_in[5];
    const float* bc0 = (const float*)d_in[6];
    const float* Wg1 = (const float*)d_in[7];
    const float* bg1 = (const float*)d_in[8];
    const float* Wc1 = (const float*)d_in[9];
    const float* bc1 = (const float*)d_in[10];
    const float* Wp  = (const float*)d_in[11];
    const float* bp  = (const float*)d_in[12];
    float* out = (float*)d_out;

    char* ws = (char*)d_ws;
    unsigned short* Tg = (unsigned short*)ws;              // 4096 B
    signed char* Qg0 = (signed char*)(ws + 4096);          // 3*256*192 = 147456
    signed char* Qc0 = (signed char*)(ws + 151552);        // 3*128*192 =  73728
    signed char* Qg1 = (signed char*)(ws + 225280);        // 3*256*256 = 196608
    signed char* Qc1 = (signed char*)(ws + 421888);        // 3*128*256 =  98304
    float* Sg0 = (float*)(ws + 520192);                    // 768*4
    float* Sc0 = (float*)(ws + 523264);                    // 384*4
    float* Sg1 = (float*)(ws + 524800);                    // 768*4
    float* Sc1 = (float*)(ws + 527872);                    // 384*4

    tprime_kernel<<<1, 256, 0, stream>>>(S, Tg);
    wscale_kernel<<<3, 256, 0, stream>>>(Wg0, Sg0, 129, 256);
    wscale_kernel<<<2, 256, 0, stream>>>(Wc0, Sc0, 129, 128);
    wscale_kernel<<<3, 256, 0, stream>>>(Wg1, Sg1, 256, 256);
    wscale_kernel<<<2, 256, 0, stream>>>(Wc1, Sc1, 256, 128);
    wquant_kernel<<<(3*256*192+255)/256, 256, 0, stream>>>(Wg0, Sg0, Qg0, 129, 256, 192, 64);
    wquant_kernel<<<(3*128*192+255)/256, 256, 0, stream>>>(Wc0, Sc0, Qc0, 129, 128, 192, 64);
    wquant_kernel<<<(3*256*256+255)/256, 256, 0, stream>>>(Wg1, Sg1, Qg1, 256, 256, 256, 128);
    wquant_kernel<<<(3*128*256+255)/256, 256, 0, stream>>>(Wc1, Sc1, Qc1, 256, 128, 256, 128);

    hipFuncSetAttribute((const void*)dcgru_persistent,
                        hipFuncAttributeMaxDynamicSharedMemorySize, LDS_BYTES);

    dcgru_persistent<<<NBLK, NT, LDS_BYTES, stream>>>(
        ihs, Qg0, Sg0, bg0, Qc0, Sc0, bc0, Qg1, Sg1, bg1, Qc1, Sc1, bc1,
        Wp, bp, Tg, out);
}